// Round 12
// baseline (286.563 us; speedup 1.0000x reference)
//
#include <hip/hip_runtime.h>
#include <cmath>

// ---------------- problem constants ----------------
#define NLAYERS 100      // hidden layers (scan)
#define DIN     64       // input features
#define WDIM    100      // hidden width
#define NPAD    112      // padded N (7 tiles of 16)
#define NT      7        // n tiles
#define ROWS    48       // 3 independent 16-row blocks per wave, phase-rotated
#define PSTR    136      // f16 plane row stride (272 B: b128-aligned, pad cols 112..127)
#define PLANE   (16 * PSTR)   // one 16-row hi plane in halves (4352 B); 3 planes total

typedef _Float16 half8 __attribute__((ext_vector_type(8)));
typedef _Float16 half2v __attribute__((ext_vector_type(2)));
typedef __fp16   fp16x2 __attribute__((ext_vector_type(2)));
typedef float    f32x4 __attribute__((ext_vector_type(4)));

// ---------------- workspace layout ----------------
// wsh layout: [l][ks][nt][lane][8] -- frag stride 512 halves (1024 B):
// imm-offset weight loads, no per-load VALU address math.
#define WSH_LAYER_HALVES (4 * NT * 64 * 8)               // 14336 halves per hidden layer
#define WSH_HALVES       (NLAYERS * WSH_LAYER_HALVES)    // 1,433,600
#define W0_HALVES        (2 * NT * 64 * 8)               // 7168 (input layer, K=64)
#define BPAD_FLOATS      ((NLAYERS + 1) * NPAD)          // 11312 (row 0 = b_in acc init)
#define OFF_BPAD_B       ((WSH_HALVES + W0_HALVES) * 2)  // bytes, 16-aligned
#define OFF_WOUT_B       (OFF_BPAD_B + BPAD_FLOATS * 4)  // bytes, 16-aligned
#define TOTAL_PREP       (WSH_HALVES + W0_HALVES + BPAD_FLOATS + NPAD)

// ============================================================
// Prep: shuffle weights into MFMA A-operand order (f16), operand-swapped:
// within a frag, lane(q,l15), elem j holds W[k=ks*32+q*8+j][n=nt*16+l15].
// Frag storage order: [l][ks][nt] (nt innermost, 1024 B stride).
// Row k==112 of each hidden-layer fragment = layer bias (h col 112 == 1.0).
// ============================================================
__global__ void actor_prep(const float* __restrict__ Win, const float* __restrict__ bin,
                           const float* __restrict__ Ws,  const float* __restrict__ bs,
                           const float* __restrict__ Wout,
                           _Float16* __restrict__ wsh, _Float16* __restrict__ w0sh,
                           float* __restrict__ bpad, float* __restrict__ woutp) {
    int t = blockIdx.x * 256 + threadIdx.x;
    if (t < WSH_HALVES) {                       // hidden-layer weights (+ bias row at k=112)
        int j    = t & 7;
        int lane = (t >> 3) & 63;
        int fid  = t >> 9;                      // (l*4 + ks)*7 + nt
        int nt   = fid % 7;
        int r2   = fid / 7;
        int ks   = r2 & 3;
        int l    = r2 >> 2;
        int qq = lane >> 4, ll = lane & 15;
        int k = ks * 32 + qq * 8 + j;
        int n = nt * 16 + ll;
        float v = 0.f;
        if (k < WDIM && n < WDIM)       v = Ws[(l * WDIM + k) * WDIM + n];
        else if (k == 112 && n < WDIM)  v = bs[l * WDIM + n];   // bias row
        wsh[t] = (_Float16)v;
        return;
    }
    int t2 = t - WSH_HALVES;
    if (t2 < W0_HALVES) {                       // input layer weights, [ks][nt] frag order
        int j    = t2 & 7;
        int lane = (t2 >> 3) & 63;
        int fid  = t2 >> 9;                     // ks*7 + nt
        int nt   = fid % 7;
        int ks   = fid / 7;
        int qq = lane >> 4, ll = lane & 15;
        int k = ks * 32 + qq * 8 + j;
        int n = nt * 16 + ll;
        float v = (k < DIN && n < WDIM) ? Win[k * WDIM + n] : 0.f;
        w0sh[t2] = (_Float16)v;
        return;
    }
    int t3 = t2 - W0_HALVES;
    if (t3 < BPAD_FLOATS) {                     // padded biases: row 0 = b_in
        int l = t3 / NPAD, c = t3 % NPAD;
        float v = 0.f;
        if (c < WDIM) v = (l == 0) ? bin[c] : bs[(l - 1) * WDIM + c];
        bpad[t3] = v;
        return;
    }
    int t4 = t3 - BPAD_FLOATS;
    if (t4 < NPAD) woutp[t4] = (t4 < WDIM) ? Wout[t4] : 0.f;
}

// split fp32 -> hi/lo fp16 (layer-0 input only: keep input fidelity)
__device__ __forceinline__ void split8(const float* __restrict__ p, half8& hi, half8& lo) {
    f32x4 u0 = *(const f32x4*)p;
    f32x4 u1 = *(const f32x4*)(p + 4);
    float v[8] = {u0[0], u0[1], u0[2], u0[3], u1[0], u1[1], u1[2], u1[3]};
#pragma unroll
    for (int e = 0; e < 8; e += 2) {
        fp16x2 h = __builtin_amdgcn_cvt_pkrtz(v[e], v[e + 1]);
        float r0 = v[e]     - (float)h[0];
        float r1 = v[e + 1] - (float)h[1];
        fp16x2 l = __builtin_amdgcn_cvt_pkrtz(r0, r1);
        hi[e] = (_Float16)h[0]; hi[e + 1] = (_Float16)h[1];
        lo[e] = (_Float16)l[0]; lo[e + 1] = (_Float16)l[1];
    }
}

// epilogue one C-tile: RNE f16 cvt, packed-f16 leaky, single b64 store
__device__ __forceinline__ void ep_tile(const f32x4 a, _Float16* __restrict__ d) {
    half2v p01, p23;
    p01[0] = (_Float16)a[0]; p01[1] = (_Float16)a[1];
    p23[0] = (_Float16)a[2]; p23[1] = (_Float16)a[3];
    const half2v slope = {(_Float16)0.01f, (_Float16)0.01f};
    p01 = __builtin_elementwise_max(p01, p01 * slope);
    p23 = __builtin_elementwise_max(p23, p23 * slope);
    uint2 w;
    w.x = __builtin_bit_cast(unsigned, p01);
    w.y = __builtin_bit_cast(unsigned, p23);
    *reinterpret_cast<uint2*>(d) = w;                    // ds_write_b64
}

// ============================================================
// Main: one wave/block, THREE independent 16-row blocks per wave,
// phase-ROTATED one third of a layer apart (extends the r10 phase-split
// win; r11 analysis showed the per-wave 28 KB/layer weight stream made
// L1 the critical pipe at 32 rows/wave — 48 rows cuts L1 traffic 1/3):
//   Phase A: mfma0(L) reads plane0 || epi1(L-1): acc1 -> plane1
//   Phase B: mfma1(L) reads plane1 || epi2(L-1): acc2 -> plane2
//   Phase C: mfma2(L) reads plane2 || epi0(L): acc0 -> plane0
//                                  || prefetch W(L+1) into wb
// All streams in a phase are data-independent -> co-issued. Full layer
// W-frags register-resident (wb[4][7]), loaded ONCE per layer for all 3
// blocks. HI-ONLY f16 activations (absmax 0.094, r8-r11); bias rides W
// row k=112 vs h col 112 == 1.0. Heads from final fp32 accs. No barriers.
// Grid 1366 (tail block row-clamped). 2 waves/SIMD max (VGPR-bound).
// ============================================================
__global__ __launch_bounds__(64, 2)
void actor_main(const float* __restrict__ x,
                const _Float16* __restrict__ wsh,
                const _Float16* __restrict__ w0sh,
                const float* __restrict__ bpad,
                const float* __restrict__ woutp,
                const float* __restrict__ bout,
                float* __restrict__ out, int nrows) {
    __shared__ _Float16 hp[3 * PLANE];   // plane b = block b
    const int lane = threadIdx.x;
    const int q = lane >> 4, l15 = lane & 15;
    const int rowbase = blockIdx.x * ROWS;

    f32x4 acc0[NT], acc1[NT], acc2[NT];
    half8 wb[4][NT];                 // FULL layer of W fragments, register-resident
    const f32x4 zero4 = {0.f, 0.f, 0.f, 0.f};

    // ---- pad init: cols 112..127 zero in all 3 planes, col 112 = 1.0 ----
    if (lane < 48) {
        const int pl = lane >> 4, row = lane & 15;
        const half8 z = {0, 0, 0, 0, 0, 0, 0, 0};
        *(half8*)(hp + pl * PLANE + row * PSTR + 112) = z;
        *(half8*)(hp + pl * PLANE + row * PSTR + 120) = z;
        hp[pl * PLANE + row * PSTR + 112] = (_Float16)1.0f;
    }

    // ---- input layer (K=64): load w0 frags once, mfma all 3 blocks ----
#pragma unroll
    for (int ks = 0; ks < 2; ++ks)
#pragma unroll
        for (int nt = 0; nt < NT; ++nt)
            wb[ks][nt] = *(const half8*)(w0sh + (ks * 7 + nt) * 512 + lane * 8);
#pragma unroll
    for (int nt = 0; nt < NT; ++nt) {
        f32x4 b = *(const f32x4*)(bpad + nt * 16 + q * 4);
        acc0[nt] = b; acc1[nt] = b; acc2[nt] = b;
    }
#pragma unroll
    for (int blk = 0; blk < 3; ++blk) {
        int row = rowbase + blk * 16 + l15;
        if (row > nrows - 1) row = nrows - 1;          // tail clamp (dup compute)
        const float* xr = x + (long)row * DIN;
#pragma unroll
        for (int ks = 0; ks < 2; ++ks) {
            half8 xhi, xlo;
            split8(xr + ks * 32 + q * 8, xhi, xlo);
            f32x4* a = (blk == 0) ? acc0 : (blk == 1) ? acc1 : acc2;
#pragma unroll
            for (int nt = 0; nt < NT; ++nt) {
                a[nt] = __builtin_amdgcn_mfma_f32_16x16x32_f16(wb[ks][nt], xhi, a[nt], 0, 0, 0);
                a[nt] = __builtin_amdgcn_mfma_f32_16x16x32_f16(wb[ks][nt], xlo, a[nt], 0, 0, 0);
            }
        }
    }
    // prefetch W(0); epi0 -> plane0 (epi1/epi2 deferred into layer-0 phases A/B)
#pragma unroll
    for (int ks = 0; ks < 4; ++ks) {
        const _Float16* wk = wsh + (ks * 7) * 512;
#pragma unroll
        for (int nt = 0; nt < NT; ++nt)
            wb[ks][nt] = *(const half8*)(wk + nt * 512 + lane * 8);
    }
#pragma unroll
    for (int nt = 0; nt < NT; ++nt)
        ep_tile(acc0[nt], hp + l15 * PSTR + nt * 16 + q * 4);

    // ---------------- 100 hidden layers, 3-phase rotation ----------------
    // loop-top invariant: plane0 = act(L-1,b0); acc1 = pre(L-1,b1);
    //                     acc2 = pre(L-1,b2); wb = W(L)
#pragma unroll 1
    for (int l = 0; l < NLAYERS; ++l) {
        const _Float16* wn = wsh + (l < NLAYERS - 1 ? l + 1 : l) * WSH_LAYER_HALVES;

        // ---- Phase A: mfma0(L) || epi1(L-1) ----
        {
#pragma unroll
            for (int nt = 0; nt < NT; ++nt) acc0[nt] = zero4;
            _Float16* d1 = hp + PLANE + l15 * PSTR + q * 4;
#pragma unroll
            for (int ks = 0; ks < 4; ++ks) {
                half8 b0 = *(const half8*)(hp + l15 * PSTR + ks * 32 + q * 8);
#pragma unroll
                for (int nt = 0; nt < NT; ++nt)
                    acc0[nt] = __builtin_amdgcn_mfma_f32_16x16x32_f16(wb[ks][nt], b0, acc0[nt], 0, 0, 0);
                ep_tile(acc1[2 * ks], d1 + (2 * ks) * 16);
                if (ks < 3) ep_tile(acc1[2 * ks + 1], d1 + (2 * ks + 1) * 16);
            }
        }
        // ---- Phase B: mfma1(L) || epi2(L-1) ----
        {
#pragma unroll
            for (int nt = 0; nt < NT; ++nt) acc1[nt] = zero4;
            _Float16* d2 = hp + 2 * PLANE + l15 * PSTR + q * 4;
#pragma unroll
            for (int ks = 0; ks < 4; ++ks) {
                half8 b1 = *(const half8*)(hp + PLANE + l15 * PSTR + ks * 32 + q * 8);
#pragma unroll
                for (int nt = 0; nt < NT; ++nt)
                    acc1[nt] = __builtin_amdgcn_mfma_f32_16x16x32_f16(wb[ks][nt], b1, acc1[nt], 0, 0, 0);
                ep_tile(acc2[2 * ks], d2 + (2 * ks) * 16);
                if (ks < 3) ep_tile(acc2[2 * ks + 1], d2 + (2 * ks + 1) * 16);
            }
        }
        // ---- Phase C: mfma2(L) || epi0(L) || prefetch W(L+1) ----
        {
#pragma unroll
            for (int nt = 0; nt < NT; ++nt) acc2[nt] = zero4;
            _Float16* d0 = hp + l15 * PSTR + q * 4;
#pragma unroll
            for (int ks = 0; ks < 4; ++ks) {
                half8 b2 = *(const half8*)(hp + 2 * PLANE + l15 * PSTR + ks * 32 + q * 8);
#pragma unroll
                for (int nt = 0; nt < NT; ++nt)
                    acc2[nt] = __builtin_amdgcn_mfma_f32_16x16x32_f16(wb[ks][nt], b2, acc2[nt], 0, 0, 0);
                // wb[ks] dead for this layer: refill with W(L+1)[ks]
                const _Float16* wk = wn + (ks * 7) * 512;
#pragma unroll
                for (int nt = 0; nt < NT; ++nt)
                    wb[ks][nt] = *(const half8*)(wk + nt * 512 + lane * 8);
                ep_tile(acc0[2 * ks], d0 + (2 * ks) * 16);
                if (ks < 3) ep_tile(acc0[2 * ks + 1], d0 + (2 * ks + 1) * 16);
            }
        }
        // acc0/1/2 still hold pre(L) after the final iteration (drains copy, not move)
    }

    // ---------------- heads: leaky + dot(W_out) from fp32 accs ----------------
#pragma unroll
    for (int blk = 0; blk < 3; ++blk) {
        const f32x4* a = (blk == 0) ? acc0 : (blk == 1) ? acc1 : acc2;
        float s = 0.f;
#pragma unroll
        for (int nt = 0; nt < NT; ++nt) {
            f32x4 w4 = *(const f32x4*)(woutp + nt * 16 + q * 4);
#pragma unroll
            for (int r = 0; r < 4; ++r) {
                float v = fmaxf(a[nt][r], 0.01f * a[nt][r]);
                s += v * w4[r];
            }
        }
        s += __shfl_xor(s, 16);
        s += __shfl_xor(s, 32);
        const int row = rowbase + blk * 16 + l15;
        if (q == 0 && row < nrows) {
            float aa = s + bout[0];
            float t = tanhf(aa);
            out[row] = t * 4.5f + 5.5f;   // (tanh+1)/2*9 + 1
        }
    }
}

extern "C" void kernel_launch(void* const* d_in, const int* in_sizes, int n_in,
                              void* d_out, int out_size, void* d_ws, size_t ws_size,
                              hipStream_t stream) {
    const float* x    = (const float*)d_in[0];
    const float* Win  = (const float*)d_in[1];
    const float* bin  = (const float*)d_in[2];
    const float* Ws   = (const float*)d_in[3];
    const float* bs   = (const float*)d_in[4];
    const float* Wout = (const float*)d_in[5];
    const float* bout = (const float*)d_in[6];
    float* out = (float*)d_out;

    char* ws = (char*)d_ws;
    _Float16* wsh  = (_Float16*)ws;
    _Float16* w0sh = wsh + WSH_HALVES;
    float* bpad  = (float*)(ws + OFF_BPAD_B);
    float* woutp = (float*)(ws + OFF_WOUT_B);

    hipLaunchKernelGGL(actor_prep, dim3((TOTAL_PREP + 255) / 256), dim3(256), 0, stream,
                       Win, bin, Ws, bs, Wout, wsh, w0sh, bpad, woutp);

    const int nrows = in_sizes[0] / DIN;   // 65536
    const int grid = (nrows + ROWS - 1) / ROWS;   // 1366 (tail clamped in-kernel)
    hipLaunchKernelGGL(actor_main, dim3(grid), dim3(64), 0, stream,
                       x, wsh, w0sh, bpad, woutp, bout, out, nrows);
}

// Round 13
// 266.817 us; speedup vs baseline: 1.0740x; 1.0740x over previous
//
#include <hip/hip_runtime.h>
#include <cmath>

// ---------------- problem constants ----------------
#define NLAYERS 100      // hidden layers (scan)
#define DIN     64       // input features
#define WDIM    100      // hidden width
#define NPAD    112      // padded N (7 tiles of 16)
#define NT      7        // n tiles
#define ROWS    32       // 2 independent 16-row blocks per wave, phase-shifted
#define PSTR    136      // f16 plane row stride (272 B: b128-aligned, pad cols 112..127)
#define PLANE   (16 * PSTR)   // one 16-row hi plane in halves (4352 B); 2 planes total

typedef _Float16 half8 __attribute__((ext_vector_type(8)));
typedef _Float16 half2v __attribute__((ext_vector_type(2)));
typedef __fp16   fp16x2 __attribute__((ext_vector_type(2)));
typedef float    f32x4 __attribute__((ext_vector_type(4)));

// ---------------- workspace layout ----------------
// wsh layout: [l][ks][nt][lane][8] -- frag stride 512 halves (1024 B):
// imm-offset weight loads, no per-load VALU address math.
#define WSH_LAYER_HALVES (4 * NT * 64 * 8)               // 14336 halves per hidden layer
#define WSH_HALVES       (NLAYERS * WSH_LAYER_HALVES)    // 1,433,600
#define W0_HALVES        (2 * NT * 64 * 8)               // 7168 (input layer, K=64)
#define BPAD_FLOATS      ((NLAYERS + 1) * NPAD)          // 11312 (row 0 = b_in acc init)
#define OFF_BPAD_B       ((WSH_HALVES + W0_HALVES) * 2)  // bytes, 16-aligned
#define OFF_WOUT_B       (OFF_BPAD_B + BPAD_FLOATS * 4)  // bytes, 16-aligned
#define TOTAL_PREP       (WSH_HALVES + W0_HALVES + BPAD_FLOATS + NPAD)

// ============================================================
// Prep: shuffle weights into MFMA A-operand order (f16), operand-swapped:
// within a frag, lane(q,l15), elem j holds W[k=ks*32+q*8+j][n=nt*16+l15].
// Frag storage order: [l][ks][nt] (nt innermost, 1024 B stride).
// Row k==112 of each hidden-layer fragment = layer bias (h col 112 == 1.0).
// ============================================================
__global__ void actor_prep(const float* __restrict__ Win, const float* __restrict__ bin,
                           const float* __restrict__ Ws,  const float* __restrict__ bs,
                           const float* __restrict__ Wout,
                           _Float16* __restrict__ wsh, _Float16* __restrict__ w0sh,
                           float* __restrict__ bpad, float* __restrict__ woutp) {
    int t = blockIdx.x * 256 + threadIdx.x;
    if (t < WSH_HALVES) {                       // hidden-layer weights (+ bias row at k=112)
        int j    = t & 7;
        int lane = (t >> 3) & 63;
        int fid  = t >> 9;                      // (l*4 + ks)*7 + nt
        int nt   = fid % 7;
        int r2   = fid / 7;
        int ks   = r2 & 3;
        int l    = r2 >> 2;
        int qq = lane >> 4, ll = lane & 15;
        int k = ks * 32 + qq * 8 + j;
        int n = nt * 16 + ll;
        float v = 0.f;
        if (k < WDIM && n < WDIM)       v = Ws[(l * WDIM + k) * WDIM + n];
        else if (k == 112 && n < WDIM)  v = bs[l * WDIM + n];   // bias row
        wsh[t] = (_Float16)v;
        return;
    }
    int t2 = t - WSH_HALVES;
    if (t2 < W0_HALVES) {                       // input layer weights, [ks][nt] frag order
        int j    = t2 & 7;
        int lane = (t2 >> 3) & 63;
        int fid  = t2 >> 9;                     // ks*7 + nt
        int nt   = fid % 7;
        int ks   = fid / 7;
        int qq = lane >> 4, ll = lane & 15;
        int k = ks * 32 + qq * 8 + j;
        int n = nt * 16 + ll;
        float v = (k < DIN && n < WDIM) ? Win[k * WDIM + n] : 0.f;
        w0sh[t2] = (_Float16)v;
        return;
    }
    int t3 = t2 - W0_HALVES;
    if (t3 < BPAD_FLOATS) {                     // padded biases: row 0 = b_in
        int l = t3 / NPAD, c = t3 % NPAD;
        float v = 0.f;
        if (c < WDIM) v = (l == 0) ? bin[c] : bs[(l - 1) * WDIM + c];
        bpad[t3] = v;
        return;
    }
    int t4 = t3 - BPAD_FLOATS;
    if (t4 < NPAD) woutp[t4] = (t4 < WDIM) ? Wout[t4] : 0.f;
}

// split fp32 -> hi/lo fp16 (layer-0 input only: keep input fidelity)
__device__ __forceinline__ void split8(const float* __restrict__ p, half8& hi, half8& lo) {
    f32x4 u0 = *(const f32x4*)p;
    f32x4 u1 = *(const f32x4*)(p + 4);
    float v[8] = {u0[0], u0[1], u0[2], u0[3], u1[0], u1[1], u1[2], u1[3]};
#pragma unroll
    for (int e = 0; e < 8; e += 2) {
        fp16x2 h = __builtin_amdgcn_cvt_pkrtz(v[e], v[e + 1]);
        float r0 = v[e]     - (float)h[0];
        float r1 = v[e + 1] - (float)h[1];
        fp16x2 l = __builtin_amdgcn_cvt_pkrtz(r0, r1);
        hi[e] = (_Float16)h[0]; hi[e + 1] = (_Float16)h[1];
        lo[e] = (_Float16)l[0]; lo[e + 1] = (_Float16)l[1];
    }
}

// epilogue one C-tile: RNE f16 cvt, packed-f16 leaky, single b64 store
__device__ __forceinline__ void ep_tile(const f32x4 a, _Float16* __restrict__ d) {
    half2v p01, p23;
    p01[0] = (_Float16)a[0]; p01[1] = (_Float16)a[1];
    p23[0] = (_Float16)a[2]; p23[1] = (_Float16)a[3];
    const half2v slope = {(_Float16)0.01f, (_Float16)0.01f};
    p01 = __builtin_elementwise_max(p01, p01 * slope);
    p23 = __builtin_elementwise_max(p23, p23 * slope);
    uint2 w;
    w.x = __builtin_bit_cast(unsigned, p01);
    w.y = __builtin_bit_cast(unsigned, p23);
    *reinterpret_cast<uint2*>(d) = w;                    // ds_write_b64
}

// ============================================================
// Main: one wave/block, TWO independent 16-row blocks per wave, executed
// half a layer out of phase (r10 structure). r13 change, from the r12
// diagnostic (per-wave layer wall ~5.2K cyc regardless of MFMA count =>
// latency-bound on the DS chain; DS ops complete IN ORDER, so per-ks
// ds_reads interleaved among epi ds_writes eat write-drain + read
// latency 8x/layer):
//   * ALL 4 B-fragment ds_read_b128 of a phase are HOISTED to the phase
//     top, issued back-to-back before any epi write queues behind them.
//   * Two epi tiles (VALU + writes that queue AFTER the reads) run
//     before the first MFMA to cover the residual read latency.
// Full layer W-frags register-resident (wb[4][7]), refilled during
// phase B. HI-ONLY f16 activations (absmax 0.094, r8-r12); bias rides
// W row k=112 vs h col 112 == 1.0. Heads from final fp32 accs.
// No barriers. 2048 blocks = 2 waves/SIMD.
// ============================================================
__global__ __launch_bounds__(64, 2)
void actor_main(const float* __restrict__ x,
                const _Float16* __restrict__ wsh,
                const _Float16* __restrict__ w0sh,
                const float* __restrict__ bpad,
                const float* __restrict__ woutp,
                const float* __restrict__ bout,
                float* __restrict__ out) {
    __shared__ _Float16 hp[2 * PLANE];   // plane0 = block0, plane1 = block1
    const int lane = threadIdx.x;
    const int q = lane >> 4, l15 = lane & 15;
    const int rowbase = blockIdx.x * ROWS;

    f32x4 acc0[NT], acc1[NT];
    half8 wb[4][NT];                 // FULL layer of W fragments, register-resident
    const f32x4 zero4 = {0.f, 0.f, 0.f, 0.f};

    // ---- pad init: cols 112..127 zero in both planes, col 112 = 1.0 (bias mult) ----
    if (lane < 32) {
        const int pl = lane >> 4, row = lane & 15;
        const half8 z = {0, 0, 0, 0, 0, 0, 0, 0};
        *(half8*)(hp + pl * PLANE + row * PSTR + 112) = z;
        *(half8*)(hp + pl * PLANE + row * PSTR + 120) = z;
        hp[pl * PLANE + row * PSTR + 112] = (_Float16)1.0f;
    }

    // ---- input layer (K=64): load w0 frags once, mfma both blocks ----
#pragma unroll
    for (int ks = 0; ks < 2; ++ks)
#pragma unroll
        for (int nt = 0; nt < NT; ++nt)
            wb[ks][nt] = *(const half8*)(w0sh + (ks * 7 + nt) * 512 + lane * 8);
#pragma unroll
    for (int nt = 0; nt < NT; ++nt) {
        f32x4 b = *(const f32x4*)(bpad + nt * 16 + q * 4);
        acc0[nt] = b;
        acc1[nt] = b;
    }
#pragma unroll
    for (int ks = 0; ks < 2; ++ks) {           // block0 input mfma
        half8 xhi, xlo;
        split8(x + (rowbase + l15) * DIN + ks * 32 + q * 8, xhi, xlo);
#pragma unroll
        for (int nt = 0; nt < NT; ++nt) {
            acc0[nt] = __builtin_amdgcn_mfma_f32_16x16x32_f16(wb[ks][nt], xhi, acc0[nt], 0, 0, 0);
            acc0[nt] = __builtin_amdgcn_mfma_f32_16x16x32_f16(wb[ks][nt], xlo, acc0[nt], 0, 0, 0);
        }
    }
#pragma unroll
    for (int ks = 0; ks < 2; ++ks) {           // block1 input mfma
        half8 xhi, xlo;
        split8(x + (rowbase + 16 + l15) * DIN + ks * 32 + q * 8, xhi, xlo);
#pragma unroll
        for (int nt = 0; nt < NT; ++nt) {
            acc1[nt] = __builtin_amdgcn_mfma_f32_16x16x32_f16(wb[ks][nt], xhi, acc1[nt], 0, 0, 0);
            acc1[nt] = __builtin_amdgcn_mfma_f32_16x16x32_f16(wb[ks][nt], xlo, acc1[nt], 0, 0, 0);
        }
    }
    // prefetch W(0) into all 4 wb slots (latency covered by epi0 below)
#pragma unroll
    for (int ks = 0; ks < 4; ++ks) {
        const _Float16* wk = wsh + (ks * 7) * 512;
#pragma unroll
        for (int nt = 0; nt < NT; ++nt)
            wb[ks][nt] = *(const half8*)(wk + nt * 512 + lane * 8);
    }
    // epi0 -> hp plane0 (block1's epi deferred into layer-0 phase A)
#pragma unroll
    for (int nt = 0; nt < NT; ++nt)
        ep_tile(acc0[nt], hp + l15 * PSTR + nt * 16 + q * 4);

    // ---------------- 100 hidden layers, phase-split ----------------
    // loop-top invariant: plane0 = act(L-1,b0); acc1 = pre(L-1,b1); wb = W(L)
#pragma unroll 1
    for (int l = 0; l < NLAYERS; ++l) {
        const _Float16* wn = wsh + (l < NLAYERS - 1 ? l + 1 : l) * WSH_LAYER_HALVES;

        // ---- Phase A: mfma0(L) || epi1(L-1) ----
        {
            half8 bA[4];                        // HOISTED reads: issue before any write
#pragma unroll
            for (int ks = 0; ks < 4; ++ks)
                bA[ks] = *(const half8*)(hp + l15 * PSTR + ks * 32 + q * 8);
            _Float16* d1 = hp + PLANE + l15 * PSTR + q * 4;
            // two epi tiles up front: VALU + writes queued AFTER the reads
            ep_tile(acc1[0], d1 + 0 * 16);
            ep_tile(acc1[1], d1 + 1 * 16);
#pragma unroll
            for (int nt = 0; nt < NT; ++nt) acc0[nt] = zero4;
#pragma unroll
            for (int ks = 0; ks < 4; ++ks) {
#pragma unroll
                for (int nt = 0; nt < NT; ++nt)
                    acc0[nt] = __builtin_amdgcn_mfma_f32_16x16x32_f16(wb[ks][nt], bA[ks], acc0[nt], 0, 0, 0);
                if (ks < 3) {                   // remaining epi1 tiles interleaved (2,2,1)
                    ep_tile(acc1[2 * ks + 2], d1 + (2 * ks + 2) * 16);
                    if (2 * ks + 3 < NT) ep_tile(acc1[2 * ks + 3], d1 + (2 * ks + 3) * 16);
                }
            }
        }

        // ---- Phase B: mfma1(L) || epi0(L) + prefetch W(L+1) ----
        {
            half8 bB[4];                        // HOISTED reads (queue after epi1 writes)
#pragma unroll
            for (int ks = 0; ks < 4; ++ks)
                bB[ks] = *(const half8*)(hp + PLANE + l15 * PSTR + ks * 32 + q * 8);
            _Float16* d0 = hp + l15 * PSTR + q * 4;
            ep_tile(acc0[0], d0 + 0 * 16);      // acc0 complete since phase A
            ep_tile(acc0[1], d0 + 1 * 16);
#pragma unroll
            for (int nt = 0; nt < NT; ++nt) acc1[nt] = zero4;
#pragma unroll
            for (int ks = 0; ks < 4; ++ks) {
#pragma unroll
                for (int nt = 0; nt < NT; ++nt)
                    acc1[nt] = __builtin_amdgcn_mfma_f32_16x16x32_f16(wb[ks][nt], bB[ks], acc1[nt], 0, 0, 0);
                // wb[ks] dead for this layer: refill with W(L+1)[ks]
                const _Float16* wk = wn + (ks * 7) * 512;
#pragma unroll
                for (int nt = 0; nt < NT; ++nt)
                    wb[ks][nt] = *(const half8*)(wk + nt * 512 + lane * 8);
                if (ks < 3) {                   // remaining epi0 tiles interleaved (2,2,1)
                    ep_tile(acc0[2 * ks + 2], d0 + (2 * ks + 2) * 16);
                    if (2 * ks + 3 < NT) ep_tile(acc0[2 * ks + 3], d0 + (2 * ks + 3) * 16);
                }
            }
        }
        // acc0 still holds pre(L) after the final iteration
    }
    // after loop: acc0 = pre(99) block0, acc1 = pre(99) block1 (both in regs)

    // ---------------- heads: leaky + dot(W_out) from fp32 accs ----------------
#pragma unroll
    for (int blk = 0; blk < 2; ++blk) {
        float s = 0.f;
#pragma unroll
        for (int nt = 0; nt < NT; ++nt) {
            f32x4 w4 = *(const f32x4*)(woutp + nt * 16 + q * 4);
            f32x4 a = blk ? acc1[nt] : acc0[nt];
#pragma unroll
            for (int r = 0; r < 4; ++r) {
                float v = fmaxf(a[r], 0.01f * a[r]);
                s += v * w4[r];
            }
        }
        s += __shfl_xor(s, 16);
        s += __shfl_xor(s, 32);
        if (q == 0) {
            float aa = s + bout[0];
            float t = tanhf(aa);
            out[rowbase + blk * 16 + l15] = t * 4.5f + 5.5f;   // (tanh+1)/2*9 + 1
        }
    }
}

extern "C" void kernel_launch(void* const* d_in, const int* in_sizes, int n_in,
                              void* d_out, int out_size, void* d_ws, size_t ws_size,
                              hipStream_t stream) {
    const float* x    = (const float*)d_in[0];
    const float* Win  = (const float*)d_in[1];
    const float* bin  = (const float*)d_in[2];
    const float* Ws   = (const float*)d_in[3];
    const float* bs   = (const float*)d_in[4];
    const float* Wout = (const float*)d_in[5];
    const float* bout = (const float*)d_in[6];
    float* out = (float*)d_out;

    char* ws = (char*)d_ws;
    _Float16* wsh  = (_Float16*)ws;
    _Float16* w0sh = wsh + WSH_HALVES;
    float* bpad  = (float*)(ws + OFF_BPAD_B);
    float* woutp = (float*)(ws + OFF_WOUT_B);

    hipLaunchKernelGGL(actor_prep, dim3((TOTAL_PREP + 255) / 256), dim3(256), 0, stream,
                       Win, bin, Ws, bs, Wout, wsh, w0sh, bpad, woutp);

    const int nrows = in_sizes[0] / DIN;   // 65536
    hipLaunchKernelGGL(actor_main, dim3(nrows / ROWS), dim3(64), 0, stream,
                       x, wsh, w0sh, bpad, woutp, bout, out);
}

// Round 14
// 262.857 us; speedup vs baseline: 1.0902x; 1.0151x over previous
//
#include <hip/hip_runtime.h>
#include <cmath>

// ---------------- problem constants ----------------
#define NLAYERS 100      // hidden layers (scan)
#define DIN     64       // input features
#define WDIM    100      // hidden width
#define NTT     8        // total n tiles (128 cols incl bias col 112 + pads)
#define NTW     4        // n tiles per wave (wave w owns nt = 4w .. 4w+3)
#define RT      4        // row tiles per block -> 64 rows
#define ROWS    64
#define PSTR    136      // f16 plane row stride (272 B: b128-aligned)
#define RTPLANE (16 * PSTR)      // one 16-row plane, halves (2176)
#define BUF     (RT * RTPLANE)   // one h buffer (64 rows), halves (8704)

typedef _Float16 half8 __attribute__((ext_vector_type(8)));
typedef _Float16 half2v __attribute__((ext_vector_type(2)));
typedef __fp16   fp16x2 __attribute__((ext_vector_type(2)));
typedef float    f32x4 __attribute__((ext_vector_type(4)));

// ---------------- workspace layout ----------------
// wsh: [l][ks][nt8][lane][8] — frag stride 512 halves (1024 B), imm-offset loads.
// Frag (ks,nt), lane(q,l15), elem j = W[k=ks*32+q*8+j][n=nt*16+l15], with:
//   k==112 && n<100  -> layer bias   (h col 112 == 1.0)
//   k==112 && n==112 -> 1.0          (bias col self-sustains through the MFMA)
#define WSH_LAYER_HALVES (4 * NTT * 64 * 8)              // 16384
#define WSH_HALVES       (NLAYERS * WSH_LAYER_HALVES)    // 1,638,400
#define W0_HALVES        (2 * NTT * 64 * 8)              // 8192 (input layer, K=64)
#define BPAD_FLOATS      128                             // b_in padded, col112 = 1.0
#define OFF_BPAD_B       ((WSH_HALVES + W0_HALVES) * 2)
#define OFF_WOUT_B       (OFF_BPAD_B + BPAD_FLOATS * 4)
#define WOUT_FLOATS      128
#define TOTAL_PREP       (WSH_HALVES + W0_HALVES + BPAD_FLOATS + WOUT_FLOATS)

__global__ void actor_prep(const float* __restrict__ Win, const float* __restrict__ bin,
                           const float* __restrict__ Ws,  const float* __restrict__ bs,
                           const float* __restrict__ Wout,
                           _Float16* __restrict__ wsh, _Float16* __restrict__ w0sh,
                           float* __restrict__ bpad, float* __restrict__ woutp) {
    int t = blockIdx.x * 256 + threadIdx.x;
    if (t < WSH_HALVES) {                       // hidden-layer weights
        int j    = t & 7;
        int lane = (t >> 3) & 63;
        int fid  = t >> 9;                      // (l*4 + ks)*8 + nt
        int nt   = fid & 7;
        int r2   = fid >> 3;
        int ks   = r2 & 3;
        int l    = r2 >> 2;
        int k = ks * 32 + (lane >> 4) * 8 + j;
        int n = nt * 16 + (lane & 15);
        float v = 0.f;
        if (k < WDIM && n < WDIM)            v = Ws[(l * WDIM + k) * WDIM + n];
        else if (k == 112 && n < WDIM)       v = bs[l * WDIM + n];   // bias row
        else if (k == 112 && n == 112)       v = 1.0f;               // keep bias col alive
        wsh[t] = (_Float16)v;
        return;
    }
    int t2 = t - WSH_HALVES;
    if (t2 < W0_HALVES) {                       // input layer weights (K=64)
        int j    = t2 & 7;
        int lane = (t2 >> 3) & 63;
        int fid  = t2 >> 9;                     // ks*8 + nt
        int nt   = fid & 7;
        int ks   = fid >> 3;
        int k = ks * 32 + (lane >> 4) * 8 + j;
        int n = nt * 16 + (lane & 15);
        float v = (k < DIN && n < WDIM) ? Win[k * WDIM + n] : 0.f;
        w0sh[t2] = (_Float16)v;
        return;
    }
    int t3 = t2 - W0_HALVES;
    if (t3 < BPAD_FLOATS) {                     // padded b_in; col 112 = 1.0 seeds bias col
        float v = (t3 < WDIM) ? bin[t3] : (t3 == 112 ? 1.0f : 0.f);
        bpad[t3] = v;
        return;
    }
    int t4 = t3 - BPAD_FLOATS;
    if (t4 < WOUT_FLOATS) woutp[t4] = (t4 < WDIM) ? Wout[t4] : 0.f;
}

// split fp32 -> hi/lo fp16 (layer-0 input only: keep input fidelity)
__device__ __forceinline__ void split8(const float* __restrict__ p, half8& hi, half8& lo) {
    f32x4 u0 = *(const f32x4*)p;
    f32x4 u1 = *(const f32x4*)(p + 4);
    float v[8] = {u0[0], u0[1], u0[2], u0[3], u1[0], u1[1], u1[2], u1[3]};
#pragma unroll
    for (int e = 0; e < 8; e += 2) {
        fp16x2 h = __builtin_amdgcn_cvt_pkrtz(v[e], v[e + 1]);
        float r0 = v[e]     - (float)h[0];
        float r1 = v[e + 1] - (float)h[1];
        fp16x2 l = __builtin_amdgcn_cvt_pkrtz(r0, r1);
        hi[e] = (_Float16)h[0]; hi[e + 1] = (_Float16)h[1];
        lo[e] = (_Float16)l[0]; lo[e + 1] = (_Float16)l[1];
    }
}

// epilogue one C-tile: RNE f16 cvt, packed-f16 leaky, single b64 store
__device__ __forceinline__ void ep_tile(const f32x4 a, _Float16* __restrict__ d) {
    half2v p01, p23;
    p01[0] = (_Float16)a[0]; p01[1] = (_Float16)a[1];
    p23[0] = (_Float16)a[2]; p23[1] = (_Float16)a[3];
    const half2v slope = {(_Float16)0.01f, (_Float16)0.01f};
    p01 = __builtin_elementwise_max(p01, p01 * slope);
    p23 = __builtin_elementwise_max(p23, p23 * slope);
    uint2 w;
    w.x = __builtin_bit_cast(unsigned, p01);
    w.y = __builtin_bit_cast(unsigned, p23);
    *reinterpret_cast<uint2*>(d) = w;                    // ds_write_b64
}

// ============================================================
// Main: 128-thread blocks (2 waves), 64 rows. N-SPLIT across waves:
// wave w computes output tiles nt = 4w..4w+3 — halves each wave's
// weight traffic (the r13 audit: L1 return BW was the top pipe at 70%)
// while keeping 2 waves/SIMD TLP (grid 1024, 4 blocks/CU).
// h (f16 hi-only; absmax 0.094, r8-r13) lives in LDS, DOUBLE-BUFFERED
// by layer parity; one barrier/layer. Within a wave, 4 row-tiles give
// r10-style overlap: epi(L,rt-1) interleaves into mfma(L,rt); only
// epi(rt3)+barrier is exposed. Bias col 112 self-sustains via the
// W[112][112]=1.0 identity element. acc zero-init removed (C=0 MFMA).
// Heads: per-wave partial dot, combined through LDS.
// ============================================================
__global__ __launch_bounds__(128, 2)
void actor_main(const float* __restrict__ x,
                const _Float16* __restrict__ wsh,
                const _Float16* __restrict__ w0sh,
                const float* __restrict__ bpad,
                const float* __restrict__ woutp,
                const float* __restrict__ bout,
                float* __restrict__ out) {
    __shared__ _Float16 hp[2 * BUF];     // two 64-row h buffers (layer parity)
    const int lane = threadIdx.x & 63;
    const int wid  = threadIdx.x >> 6;   // 0 or 1: owns nt 4w..4w+3
    const int q = lane >> 4, l15 = lane & 15;
    const int rowbase = blockIdx.x * ROWS;
    const int ntb = wid * NTW;           // tile base

    f32x4 acc[RT][NTW];
    half8 wb[4][NTW];                    // my quarter-layer of W frags, register-resident
    const f32x4 zero4 = {0.f, 0.f, 0.f, 0.f};

    // ---- input layer (K=64): acc init = bpad (col112 -> 1.0 seed), 2 ks steps ----
#pragma unroll
    for (int ks = 0; ks < 2; ++ks)
#pragma unroll
        for (int ntl = 0; ntl < NTW; ++ntl)
            wb[ks][ntl] = *(const half8*)(w0sh + (ks * NTT + ntb + ntl) * 512 + lane * 8);
#pragma unroll
    for (int rt = 0; rt < RT; ++rt)
#pragma unroll
        for (int ntl = 0; ntl < NTW; ++ntl)
            acc[rt][ntl] = *(const f32x4*)(bpad + (ntb + ntl) * 16 + q * 4);
#pragma unroll
    for (int rt = 0; rt < RT; ++rt) {
        const float* xr = x + (rowbase + rt * 16 + l15) * DIN;
#pragma unroll
        for (int ks = 0; ks < 2; ++ks) {
            half8 xhi, xlo;
            split8(xr + ks * 32 + q * 8, xhi, xlo);
#pragma unroll
            for (int ntl = 0; ntl < NTW; ++ntl) {
                acc[rt][ntl] = __builtin_amdgcn_mfma_f32_16x16x32_f16(wb[ks][ntl], xhi, acc[rt][ntl], 0, 0, 0);
                acc[rt][ntl] = __builtin_amdgcn_mfma_f32_16x16x32_f16(wb[ks][ntl], xlo, acc[rt][ntl], 0, 0, 0);
            }
        }
    }
    // epi0 -> buffer 0 (all my tiles, all rts); prefetch W(0)
#pragma unroll
    for (int rt = 0; rt < RT; ++rt)
#pragma unroll
        for (int ntl = 0; ntl < NTW; ++ntl)
            ep_tile(acc[rt][ntl], hp + rt * RTPLANE + l15 * PSTR + (ntb + ntl) * 16 + q * 4);
#pragma unroll
    for (int ks = 0; ks < 4; ++ks)
#pragma unroll
        for (int ntl = 0; ntl < NTW; ++ntl)
            wb[ks][ntl] = *(const half8*)(wsh + (ks * NTT + ntb + ntl) * 512 + lane * 8);
    __syncthreads();

    // ---------------- 100 hidden layers ----------------
    // layer l: reads buf[l&1] (h of layer l-1), writes buf[(l+1)&1]
#pragma unroll 1
    for (int l = 0; l < NLAYERS; ++l) {
        const _Float16* rb = hp + (l & 1) * BUF;
        _Float16* wbf = hp + ((l + 1) & 1) * BUF;
        const _Float16* wn = wsh + (l < NLAYERS - 1 ? l + 1 : l) * WSH_LAYER_HALVES;

#pragma unroll
        for (int rt = 0; rt < RT; ++rt) {
            // hoisted B-frag reads (before any epi write queues behind them)
            half8 bh[4];
#pragma unroll
            for (int ks = 0; ks < 4; ++ks)
                bh[ks] = *(const half8*)(rb + rt * RTPLANE + l15 * PSTR + ks * 32 + q * 8);
            _Float16* dprev = wbf + (rt - 1) * RTPLANE + l15 * PSTR + q * 4;
#pragma unroll
            for (int ks = 0; ks < 4; ++ks) {
#pragma unroll
                for (int ntl = 0; ntl < NTW; ++ntl)
                    acc[rt][ntl] = __builtin_amdgcn_mfma_f32_16x16x32_f16(
                        wb[ks][ntl], bh[ks], (ks == 0 ? zero4 : acc[rt][ntl]), 0, 0, 0);
                // interleave: one epi tile of rt-1 per ks slot (independent of this mfma)
                if (rt >= 1)
                    ep_tile(acc[rt - 1][ks], dprev + (ntb + ks) * 16);
                // during the last rt, wb[ks] is dead after its mfma: refill with W(L+1)
                if (rt == RT - 1) {
#pragma unroll
                    for (int ntl = 0; ntl < NTW; ++ntl)
                        wb[ks][ntl] = *(const half8*)(wn + (ks * NTT + ntb + ntl) * 512 + lane * 8);
                }
            }
        }
        // tail: epi of rt3, then layer barrier
        _Float16* dlast = wbf + (RT - 1) * RTPLANE + l15 * PSTR + q * 4;
#pragma unroll
        for (int ntl = 0; ntl < NTW; ++ntl)
            ep_tile(acc[RT - 1][ntl], dlast + (ntb + ntl) * 16);
        __syncthreads();
    }
    // acc[rt][ntl] = pre-activation of layer 99 for my cols (epi of last layer wrote
    // the dead buffer; values preserved in regs for the head)

    // ---------------- heads: leaky + dot(W_out) over my cols, combine via LDS ----------------
    float part[RT];
#pragma unroll
    for (int rt = 0; rt < RT; ++rt) {
        float s = 0.f;
#pragma unroll
        for (int ntl = 0; ntl < NTW; ++ntl) {
            f32x4 w4 = *(const f32x4*)(woutp + (ntb + ntl) * 16 + q * 4);
#pragma unroll
            for (int r = 0; r < 4; ++r) {
                float a = acc[rt][ntl][r];
                float v = fmaxf(a, 0.01f * a);
                s += v * w4[r];
            }
        }
        s += __shfl_xor(s, 16);
        s += __shfl_xor(s, 32);
        part[rt] = s;
    }
    float* red = (float*)hp;             // 128 floats of scratch (h is dead)
#pragma unroll
    for (int rt = 0; rt < RT; ++rt)
        if (q == 0) red[wid * 64 + rt * 16 + l15] = part[rt];
    __syncthreads();
    {
        const int r = threadIdx.x;
        if (r < 64) {
            float tot = red[r] + red[64 + r] + bout[0];
            out[rowbase + r] = tanhf(tot) * 4.5f + 5.5f;   // (tanh+1)/2*9 + 1
        }
    }
}

extern "C" void kernel_launch(void* const* d_in, const int* in_sizes, int n_in,
                              void* d_out, int out_size, void* d_ws, size_t ws_size,
                              hipStream_t stream) {
    const float* x    = (const float*)d_in[0];
    const float* Win  = (const float*)d_in[1];
    const float* bin  = (const float*)d_in[2];
    const float* Ws   = (const float*)d_in[3];
    const float* bs   = (const float*)d_in[4];
    const float* Wout = (const float*)d_in[5];
    const float* bout = (const float*)d_in[6];
    float* out = (float*)d_out;

    char* ws = (char*)d_ws;
    _Float16* wsh  = (_Float16*)ws;
    _Float16* w0sh = wsh + WSH_HALVES;
    float* bpad  = (float*)(ws + OFF_BPAD_B);
    float* woutp = (float*)(ws + OFF_WOUT_B);

    hipLaunchKernelGGL(actor_prep, dim3((TOTAL_PREP + 255) / 256), dim3(256), 0, stream,
                       Win, bin, Ws, bs, Wout, wsh, w0sh, bpad, woutp);

    const int nrows = in_sizes[0] / DIN;   // 65536
    hipLaunchKernelGGL(actor_main, dim3(nrows / ROWS), dim3(128), 0, stream,
                       x, wsh, w0sh, bpad, woutp, bout, out);
}